// Round 7
// baseline (683.490 us; speedup 1.0000x reference)
//
#include <hip/hip_runtime.h>
#include <hip/hip_fp16.h>

#define N_ROWS 100000
#define NNODES 150000
#define D 32
#define NEDGE 5000000
#define BINSHIFT 7
#define BINSZ 128                          // nodes per bin
#define NBINS 1172                         // ceil(150000 / 128)
#define NBLK 512                           // scatter/count blocks
#define SCT 1024                           // threads per scatter/count block
#define CPB ((NEDGE + NBLK - 1) / NBLK)    // 9766 edges per block
#define NCOUNTS (NBINS * NBLK)             // 600064
#define SCAN_ITEMS 1024
#define NSCAN (NCOUNTS / SCAN_ITEMS)       // 586 (exact)
#define QSIZE 37500                        // src quartile width (2.4 MB fp16 window)

__device__ __forceinline__ int quartile(unsigned s) {
    return (s >= 2u * QSIZE) ? ((s >= 3u * QSIZE) ? 3 : 2) : ((s >= QSIZE) ? 1 : 0);
}

// ---------------- stage 1: per-(block,bin) counts matrix (no global atomics) ----------------

__global__ void count_kernel(const int* __restrict__ dst, int* __restrict__ counts) {
    __shared__ int h[NBINS];
    const int t = threadIdx.x;
    for (int b = t; b < NBINS; b += SCT) h[b] = 0;
    __syncthreads();
    const int e0 = blockIdx.x * CPB;
    const int e1 = min(e0 + CPB, NEDGE);
    for (int i = e0 + t; i < e1; i += SCT) atomicAdd(&h[dst[i] >> BINSHIFT], 1);
    __syncthreads();
    for (int b = t; b < NBINS; b += SCT) counts[b * NBLK + blockIdx.x] = h[b];
}

// ---------------- stage 2: device-wide exclusive scan of counts ----------------

__global__ void scanA(const int* __restrict__ counts, int* __restrict__ partials) {
    __shared__ int s[256];
    const int t = threadIdx.x;
    const int base = blockIdx.x * SCAN_ITEMS + t * 4;
    int sum = 0;
#pragma unroll
    for (int k = 0; k < 4; ++k) sum += counts[base + k];
    s[t] = sum;
    __syncthreads();
    for (int off = 128; off > 0; off >>= 1) {
        if (t < off) s[t] += s[t + off];
        __syncthreads();
    }
    if (t == 0) partials[blockIdx.x] = s[0];
}

__global__ void scanB(int* __restrict__ partials) {
    __shared__ int s[256];
    __shared__ int carry;
    const int t = threadIdx.x;
    if (t == 0) carry = 0;
    __syncthreads();
    for (int c = 0; c < (NSCAN + 255) / 256; ++c) {
        int idx = c * 256 + t;
        int v = (idx < NSCAN) ? partials[idx] : 0;
        s[t] = v;
        __syncthreads();
        for (int off = 1; off < 256; off <<= 1) {
            int tmp = (t >= off) ? s[t - off] : 0;
            __syncthreads();
            s[t] += tmp;
            __syncthreads();
        }
        if (idx < NSCAN) partials[idx] = carry + s[t] - v;  // exclusive
        __syncthreads();
        if (t == 0) carry += s[255];
        __syncthreads();
    }
}

__global__ void scanC(const int* __restrict__ counts, const int* __restrict__ partials,
                      int* __restrict__ bases, int* __restrict__ binPtr) {
    __shared__ int s[256];
    const int t = threadIdx.x;
    const int base = blockIdx.x * SCAN_ITEMS + t * 4;
    int c[4];
    int sum = 0;
#pragma unroll
    for (int k = 0; k < 4; ++k) { c[k] = counts[base + k]; sum += c[k]; }
    s[t] = sum;
    __syncthreads();
    for (int off = 1; off < 256; off <<= 1) {
        int v = (t >= off) ? s[t - off] : 0;
        __syncthreads();
        s[t] += v;
        __syncthreads();
    }
    int run = partials[blockIdx.x] + ((t == 0) ? 0 : s[t - 1]);
#pragma unroll
    for (int k = 0; k < 4; ++k) {
        int idx = base + k;
        bases[idx] = run;
        if ((idx & (NBLK - 1)) == 0) binPtr[idx / NBLK] = run;
        run += c[k];
    }
    if (blockIdx.x == 0 && t == 0) binPtr[NBINS] = NEDGE;
}

// ---------------- stage 3: deterministic scatter (packed (dstLocal<<18)|src) ----------------

__global__ void scatter2(const int* __restrict__ src, const int* __restrict__ dst,
                         const int* __restrict__ bases, unsigned int* __restrict__ binned) {
    __shared__ int h[NBINS];
    __shared__ int base[NBINS];
    const int t = threadIdx.x;
    for (int b = t; b < NBINS; b += SCT) {
        h[b] = 0;
        base[b] = bases[b * NBLK + blockIdx.x];
    }
    __syncthreads();
    const int e0 = blockIdx.x * CPB;
    const int e1 = min(e0 + CPB, NEDGE);
    for (int i = e0 + t; i < e1; i += SCT) {
        int dv = dst[i];
        int bn = dv >> BINSHIFT;
        int r = atomicAdd(&h[bn], 1);  // LDS rank only
        binned[base[bn] + r] = ((unsigned)(dv & (BINSZ - 1)) << 18) | (unsigned)src[i];
    }
}

// ---------------- stage 4: per-bin counting sort by (dstLocal, srcQuartile) ----------------
// Emits qrowptr[d*4+q] segment starts and srcSorted (plain src ints).

__global__ void fine_sort(const int* __restrict__ binPtr, const unsigned int* __restrict__ binned,
                          int* __restrict__ qrowptr, int* __restrict__ srcSorted) {
    __shared__ int cnt[BINSZ * 4];
    __shared__ int cur[BINSZ * 4];
    const int t = threadIdx.x;  // 512 threads, one key each
    const int bin = blockIdx.x;
    const int e0 = binPtr[bin];
    const int e1 = binPtr[bin + 1];

    cnt[t] = 0;
    __syncthreads();
    for (int e = e0 + t; e < e1; e += 512) {
        unsigned u = binned[e];
        unsigned s = u & 0x3FFFFu;
        atomicAdd(&cnt[(int)((u >> 18) << 2) | quartile(s)], 1);
    }
    __syncthreads();
    cur[t] = cnt[t];
    __syncthreads();
    for (int off = 1; off < BINSZ * 4; off <<= 1) {
        int v = (t >= off) ? cur[t - off] : 0;
        __syncthreads();
        cur[t] += v;
        __syncthreads();
    }
    {
        int excl = cur[t] - cnt[t];
        // key t -> node (bin*128 + (t>>2)), quartile (t&3); global index = bin*512 + t.
        // ghost keys past NNODES write e1 (=NEDGE for last bin) -> sentinel emerges naturally.
        qrowptr[bin * (BINSZ * 4) + t] = e0 + excl;
        cur[t] = excl;
    }
    __syncthreads();
    for (int e = e0 + t; e < e1; e += 512) {
        unsigned u = binned[e];
        unsigned s = u & 0x3FFFFu;
        int key = (int)((u >> 18) << 2) | quartile(s);
        int r = atomicAdd(&cur[key], 1);
        srcSorted[e0 + r] = (int)s;
    }
}

// ---------------- layer 0 linear: embeddings -> H0 (fp16) ----------------

__global__ void linear0(const float* __restrict__ xa, const float* __restrict__ xb,
                        const float* __restrict__ W, const float* __restrict__ b,
                        __half* __restrict__ H) {
    __shared__ float Wt[D * D];
    __shared__ float bs[D];
    const int tid = threadIdx.x;
    for (int t = tid; t < D * D; t += blockDim.x) {
        int j = t / D, k = t % D;
        Wt[k * D + j] = W[j * D + k];
    }
    if (tid < D) bs[tid] = b[tid];
    __syncthreads();

    const int row = blockIdx.x * 8 + (tid >> 5);
    const int j = tid & 31;

    float xv = (row < N_ROWS) ? xa[row * D + j] : xb[(row - N_ROWS) * D + j];

    float acc = bs[j];
#pragma unroll
    for (int k = 0; k < D; ++k) {
        float a = __shfl(xv, k, D);
        acc = fmaf(a, Wt[k * D + j], acc);
    }
    H[row * D + j] = __float2half(acc);
}

// ---------------- quartile aggregation passes ----------------
// MODE 0: acc = Hin[d] (self-loop) + sum(seg q);   write ACC
// MODE 1: acc = ACC[d] + sum(seg q);               write ACC
// MODE 2: acc = ACC[d] + sum(seg q); relu; next linear -> Hout (fp16)
// MODE 3: acc = ACC[d] + sum(seg q); relu -> out (f32)
template <int MODE>
__global__ void agg_pass(const int q, const int* __restrict__ qrowptr,
                         const int* __restrict__ srcSorted,
                         const __half* __restrict__ Hin, float* __restrict__ ACC,
                         const float* __restrict__ W, const float* __restrict__ b,
                         __half* __restrict__ Hout, float* __restrict__ out) {
    __shared__ float Wt[D * D];
    __shared__ float bs[D];
    const int tid = threadIdx.x;
    if (MODE == 2) {
        for (int t = tid; t < D * D; t += 256) {
            int j = t / D, k = t % D;
            Wt[k * D + j] = W[j * D + k];
        }
        if (tid < D) bs[tid] = b[tid];
        __syncthreads();
    }

    const int d = blockIdx.x * 8 + (tid >> 5);  // grid exact: NNODES/8
    const int j = tid & 31;

    int e = qrowptr[d * 4 + q];
    const int eEnd = qrowptr[d * 4 + q + 1];
    float acc = (MODE == 0) ? __half2float(Hin[d * D + j]) : ACC[d * D + j];

    for (; e + 3 < eEnd; e += 4) {
        const int s0 = srcSorted[e];
        const int s1 = srcSorted[e + 1];
        const int s2 = srcSorted[e + 2];
        const int s3 = srcSorted[e + 3];
        const float v0 = __half2float(Hin[s0 * D + j]);
        const float v1 = __half2float(Hin[s1 * D + j]);
        const float v2 = __half2float(Hin[s2 * D + j]);
        const float v3 = __half2float(Hin[s3 * D + j]);
        acc += v0 + v1 + v2 + v3;
    }
    for (; e < eEnd; ++e) acc += __half2float(Hin[srcSorted[e] * D + j]);

    if (MODE <= 1) {
        ACC[d * D + j] = acc;
        return;
    }
    const float xv = fmaxf(acc, 0.0f);
    if (MODE == 3) {
        out[d * D + j] = xv;
        return;
    }
    float nacc = bs[j];
#pragma unroll
    for (int k = 0; k < D; ++k) {
        float a = __shfl(xv, k, D);
        nacc = fmaf(a, Wt[k * D + j], nacc);
    }
    Hout[d * D + j] = __float2half(nacc);
}

// ---------------- launch ----------------

extern "C" void kernel_launch(void* const* d_in, const int* in_sizes, int n_in,
                              void* d_out, int out_size, void* d_ws, size_t ws_size,
                              hipStream_t stream) {
    const float* row_embed = (const float*)d_in[0];
    const float* col_embed = (const float*)d_in[1];
    const float* W0 = (const float*)d_in[2];
    const float* b0 = (const float*)d_in[3];
    const float* W1 = (const float*)d_in[4];
    const float* b1 = (const float*)d_in[5];
    const float* W2 = (const float*)d_in[6];
    const float* b2 = (const float*)d_in[7];
    const int* ei = (const int*)d_in[8];
    const int* src = ei;
    const int* dst = ei + NEDGE;
    float* out = (float*)d_out;

    // workspace carve-up (~66 MB). ACC aliases binned (binned dead after fine_sort).
    __half* H0 = (__half*)d_ws;                                       // 9.6 MB
    __half* H1 = H0 + (size_t)NNODES * D;                             // 9.6 MB
    unsigned int* binned = (unsigned int*)(H1 + (size_t)NNODES * D);  // 20 MB
    float* ACC = (float*)binned;                                      // alias (19.2 MB)
    int* srcSorted = (int*)(binned + NEDGE);                          // 20 MB
    int* counts = srcSorted + NEDGE;                                  // 2.4 MB
    int* bases = counts + NCOUNTS;                                    // 2.4 MB
    int* partials = bases + NCOUNTS;                                  // 586
    int* binPtr = partials + NSCAN;                                   // NBINS+1
    int* qrowptr = binPtr + (NBINS + 1);                              // 600064+1 ints

    const int row_grid = NNODES / 8;  // 18750 exact

    // CSR build — atomic-free counting sort by (dstBin, dstLocal, srcQuartile)
    count_kernel<<<NBLK, SCT, 0, stream>>>(dst, counts);
    scanA<<<NSCAN, 256, 0, stream>>>(counts, partials);
    scanB<<<1, 256, 0, stream>>>(partials);
    scanC<<<NSCAN, 256, 0, stream>>>(counts, partials, bases, binPtr);
    scatter2<<<NBLK, SCT, 0, stream>>>(src, dst, bases, binned);
    fine_sort<<<NBINS, 512, 0, stream>>>(binPtr, binned, qrowptr, srcSorted);

    linear0<<<row_grid, 256, 0, stream>>>(row_embed, col_embed, W0, b0, H0);

    // layer 1: H0 -> (agg+relu+W1) -> H1
    agg_pass<0><<<row_grid, 256, 0, stream>>>(0, qrowptr, srcSorted, H0, ACC, nullptr, nullptr, nullptr, nullptr);
    agg_pass<1><<<row_grid, 256, 0, stream>>>(1, qrowptr, srcSorted, H0, ACC, nullptr, nullptr, nullptr, nullptr);
    agg_pass<1><<<row_grid, 256, 0, stream>>>(2, qrowptr, srcSorted, H0, ACC, nullptr, nullptr, nullptr, nullptr);
    agg_pass<2><<<row_grid, 256, 0, stream>>>(3, qrowptr, srcSorted, H0, ACC, W1, b1, H1, nullptr);
    // layer 2: H1 -> (agg+relu+W2) -> H0
    agg_pass<0><<<row_grid, 256, 0, stream>>>(0, qrowptr, srcSorted, H1, ACC, nullptr, nullptr, nullptr, nullptr);
    agg_pass<1><<<row_grid, 256, 0, stream>>>(1, qrowptr, srcSorted, H1, ACC, nullptr, nullptr, nullptr, nullptr);
    agg_pass<1><<<row_grid, 256, 0, stream>>>(2, qrowptr, srcSorted, H1, ACC, nullptr, nullptr, nullptr, nullptr);
    agg_pass<2><<<row_grid, 256, 0, stream>>>(3, qrowptr, srcSorted, H1, ACC, W2, b2, H0, nullptr);
    // layer 3: H0 -> (agg+relu) -> out
    agg_pass<0><<<row_grid, 256, 0, stream>>>(0, qrowptr, srcSorted, H0, ACC, nullptr, nullptr, nullptr, nullptr);
    agg_pass<1><<<row_grid, 256, 0, stream>>>(1, qrowptr, srcSorted, H0, ACC, nullptr, nullptr, nullptr, nullptr);
    agg_pass<1><<<row_grid, 256, 0, stream>>>(2, qrowptr, srcSorted, H0, ACC, nullptr, nullptr, nullptr, nullptr);
    agg_pass<3><<<row_grid, 256, 0, stream>>>(3, qrowptr, srcSorted, H0, ACC, nullptr, nullptr, nullptr, out);

    (void)in_sizes; (void)n_in; (void)out_size; (void)ws_size;
}

// Round 8
// 525.831 us; speedup vs baseline: 1.2998x; 1.2998x over previous
//
#include <hip/hip_runtime.h>
#include <hip/hip_fp16.h>

#define N_ROWS 100000
#define NNODES 150000
#define D 32
#define NEDGE 5000000
#define BINSHIFT 7
#define BINSZ 128                          // nodes per bin
#define NBINS 1172                         // ceil(150000 / 128)
#define NBLK 512                           // scatter/count blocks
#define SCT 1024                           // threads per scatter/count block
#define CPB ((NEDGE + NBLK - 1) / NBLK)    // 9766 edges per block
#define NCOUNTS (NBINS * NBLK)             // 600064
#define SCAN_ITEMS 1024
#define NSCAN (NCOUNTS / SCAN_ITEMS)       // 586 (exact)

// ---------------- stage 1: per-(block,bin) counts matrix (no global atomics) ----------------

__global__ void count_kernel(const int* __restrict__ dst, int* __restrict__ counts) {
    __shared__ int h[NBINS];
    const int t = threadIdx.x;
    for (int b = t; b < NBINS; b += SCT) h[b] = 0;
    __syncthreads();
    const int e0 = blockIdx.x * CPB;
    const int e1 = min(e0 + CPB, NEDGE);
    for (int i = e0 + t; i < e1; i += SCT) atomicAdd(&h[dst[i] >> BINSHIFT], 1);
    __syncthreads();
    for (int b = t; b < NBINS; b += SCT) counts[b * NBLK + blockIdx.x] = h[b];
}

// ---------------- stage 2: device-wide exclusive scan of counts ----------------

__global__ void scanA(const int* __restrict__ counts, int* __restrict__ partials) {
    __shared__ int s[256];
    const int t = threadIdx.x;
    const int base = blockIdx.x * SCAN_ITEMS + t * 4;
    int sum = 0;
#pragma unroll
    for (int k = 0; k < 4; ++k) sum += counts[base + k];
    s[t] = sum;
    __syncthreads();
    for (int off = 128; off > 0; off >>= 1) {
        if (t < off) s[t] += s[t + off];
        __syncthreads();
    }
    if (t == 0) partials[blockIdx.x] = s[0];
}

__global__ void scanB(int* __restrict__ partials) {
    __shared__ int s[256];
    __shared__ int carry;
    const int t = threadIdx.x;
    if (t == 0) carry = 0;
    __syncthreads();
    for (int c = 0; c < (NSCAN + 255) / 256; ++c) {
        int idx = c * 256 + t;
        int v = (idx < NSCAN) ? partials[idx] : 0;
        s[t] = v;
        __syncthreads();
        for (int off = 1; off < 256; off <<= 1) {
            int tmp = (t >= off) ? s[t - off] : 0;
            __syncthreads();
            s[t] += tmp;
            __syncthreads();
        }
        if (idx < NSCAN) partials[idx] = carry + s[t] - v;  // exclusive
        __syncthreads();
        if (t == 0) carry += s[255];
        __syncthreads();
    }
}

__global__ void scanC(const int* __restrict__ counts, const int* __restrict__ partials,
                      int* __restrict__ bases, int* __restrict__ binPtr) {
    __shared__ int s[256];
    const int t = threadIdx.x;
    const int base = blockIdx.x * SCAN_ITEMS + t * 4;
    int c[4];
    int sum = 0;
#pragma unroll
    for (int k = 0; k < 4; ++k) { c[k] = counts[base + k]; sum += c[k]; }
    s[t] = sum;
    __syncthreads();
    for (int off = 1; off < 256; off <<= 1) {
        int v = (t >= off) ? s[t - off] : 0;
        __syncthreads();
        s[t] += v;
        __syncthreads();
    }
    int run = partials[blockIdx.x] + ((t == 0) ? 0 : s[t - 1]);
#pragma unroll
    for (int k = 0; k < 4; ++k) {
        int idx = base + k;
        bases[idx] = run;
        if ((idx & (NBLK - 1)) == 0) binPtr[idx / NBLK] = run;
        run += c[k];
    }
    if (blockIdx.x == 0 && t == 0) binPtr[NBINS] = NEDGE;
}

// ---------------- stage 3: LDS-staged scatter — bin-sorted, piecewise-coalesced stores ----------------
// Stage packed words in LDS in bin order, then copy out linearly; slot->bin via binary search.

__global__ void __launch_bounds__(SCT, 2)
scatter3(const int* __restrict__ src, const int* __restrict__ dst,
         const int* __restrict__ bases, unsigned int* __restrict__ binned) {
    __shared__ int cnt[NBINS];          // counts, then cursor (slot allocator)
    __shared__ int lb[NBINS + 1];       // local exclusive prefix (slot base per bin)
    __shared__ int gb[NBINS];           // global base per bin for this block
    __shared__ int ssum[SCT];           // scan workspace
    __shared__ unsigned int staged[CPB];

    const int t = threadIdx.x;
    const int e0 = blockIdx.x * CPB;
    const int e1 = min(e0 + CPB, NEDGE);
    const int n = e1 - e0;

    for (int b = t; b < NBINS; b += SCT) {
        cnt[b] = 0;
        gb[b] = bases[b * NBLK + blockIdx.x];
    }
    __syncthreads();
    for (int i = e0 + t; i < e1; i += SCT) atomicAdd(&cnt[dst[i] >> BINSHIFT], 1);
    __syncthreads();

    // block-wide exclusive scan of cnt[0..NBINS) -> lb (pairs per thread, Hillis-Steele on 1024)
    const int i0 = 2 * t, i1 = 2 * t + 1;
    const int c0 = (i0 < NBINS) ? cnt[i0] : 0;
    const int c1 = (i1 < NBINS) ? cnt[i1] : 0;
    ssum[t] = c0 + c1;
    __syncthreads();
    for (int off = 1; off < SCT; off <<= 1) {
        int v = (t >= off) ? ssum[t - off] : 0;
        __syncthreads();
        ssum[t] += v;
        __syncthreads();
    }
    const int excl = (t == 0) ? 0 : ssum[t - 1];
    if (i0 < NBINS) lb[i0] = excl;
    if (i1 < NBINS) lb[i1] = excl + c0;
    if (t == 0) lb[NBINS] = n;
    __syncthreads();

    // cursor = local base; scatter packed words into staged (bin-sorted order)
    for (int b = t; b < NBINS; b += SCT) cnt[b] = lb[b];
    __syncthreads();
    for (int i = e0 + t; i < e1; i += SCT) {
        const int dv = dst[i];
        const int bn = dv >> BINSHIFT;
        const int slot = atomicAdd(&cnt[bn], 1);
        staged[slot] = ((unsigned)(dv & (BINSZ - 1)) << 18) | (unsigned)src[i];
    }
    __syncthreads();

    // linear copy out: slot s -> binned[gb[bin(s)] + (s - lb[bin(s)])]
    for (int s2 = t; s2 < n; s2 += SCT) {
        int lo = 0, hi = NBINS;
        while (hi - lo > 1) {
            const int mid = (lo + hi) >> 1;
            if (lb[mid] <= s2) lo = mid; else hi = mid;
        }
        binned[gb[lo] + (s2 - lb[lo])] = staged[s2];
    }
}

// ---------------- stage 4: per-bin fine counting sort -> full CSR by dst ----------------

__global__ void fine_sort(const int* __restrict__ binPtr, const unsigned int* __restrict__ binned,
                          int* __restrict__ rowptr, int* __restrict__ srcSorted) {
    __shared__ int cnt[BINSZ];
    __shared__ int cur[BINSZ];
    const int t = threadIdx.x;  // 512 threads
    const int bin = blockIdx.x;
    const int nodeBase = bin << BINSHIFT;
    const int nNodes = min(BINSZ, NNODES - nodeBase);
    const int e0 = binPtr[bin];
    const int e1 = binPtr[bin + 1];

    if (t < BINSZ) cnt[t] = 0;
    __syncthreads();
    for (int e = e0 + t; e < e1; e += 512) atomicAdd(&cnt[binned[e] >> 18], 1);
    __syncthreads();
    if (t < BINSZ) cur[t] = cnt[t];
    __syncthreads();
    for (int off = 1; off < BINSZ; off <<= 1) {
        int v = 0;
        if (t < BINSZ && t >= off) v = cur[t - off];
        __syncthreads();
        if (t < BINSZ) cur[t] += v;
        __syncthreads();
    }
    if (t < BINSZ) {
        int excl = cur[t] - cnt[t];
        if (t < nNodes) rowptr[nodeBase + t] = e0 + excl;
        cur[t] = excl;
    }
    __syncthreads();
    for (int e = e0 + t; e < e1; e += 512) {
        unsigned u = binned[e];
        int r = atomicAdd(&cur[u >> 18], 1);
        srcSorted[e0 + r] = (int)(u & 0x3FFFFu);
    }
    if (bin == 0 && t == 0) rowptr[NNODES] = NEDGE;
}

// ---------------- per-layer compute (unfused: agg fast, linear cheap) ----------------

// h[i][j] = sum_k act(x[i][k]) * W[j][k] + b[j]; H stored fp16
// MODE 0: x = concat(row_embed, col_embed), no activation. MODE 1: x = xa (f32), ReLU on read.
template <int MODE>
__global__ void linear_kernel(const float* __restrict__ xa, const float* __restrict__ xb,
                              const float* __restrict__ W, const float* __restrict__ b,
                              __half* __restrict__ H) {
    __shared__ float Wt[D * D];
    __shared__ float bs[D];
    const int tid = threadIdx.x;
    for (int t = tid; t < D * D; t += blockDim.x) {
        int j = t / D, k = t % D;
        Wt[k * D + j] = W[j * D + k];
    }
    if (tid < D) bs[tid] = b[tid];
    __syncthreads();

    const int row = blockIdx.x * 8 + (tid >> 5);
    const int j = tid & 31;

    float xv;
    if (MODE == 0) {
        xv = (row < N_ROWS) ? xa[row * D + j] : xb[(row - N_ROWS) * D + j];
    } else {
        xv = fmaxf(xa[row * D + j], 0.0f);
    }

    float acc = bs[j];
#pragma unroll
    for (int k = 0; k < D; ++k) {
        float a = __shfl(xv, k, D);
        acc = fmaf(a, Wt[k * D + j], acc);
    }
    H[row * D + j] = __float2half(acc);
}

// One 32-lane group per dst row; fp16 gathers, f32 accumulate; unroll 8 for MLP.
template <bool RELU>
__global__ void agg_csr(const int* __restrict__ rowptr, const int* __restrict__ srcSorted,
                        const __half* __restrict__ H, float* __restrict__ OUT) {
    const int tid = threadIdx.x;
    const int d = blockIdx.x * 8 + (tid >> 5);
    const int j = tid & 31;

    int e = rowptr[d];
    const int eEnd = rowptr[d + 1];
    float acc = __half2float(H[d * D + j]);  // self-loop
    for (; e + 7 < eEnd; e += 8) {
        int s[8];
#pragma unroll
        for (int k = 0; k < 8; ++k) s[k] = srcSorted[e + k];
        float v[8];
#pragma unroll
        for (int k = 0; k < 8; ++k) v[k] = __half2float(H[s[k] * D + j]);
#pragma unroll
        for (int k = 0; k < 8; ++k) acc += v[k];
    }
    for (; e < eEnd; ++e) acc += __half2float(H[srcSorted[e] * D + j]);
    OUT[d * D + j] = RELU ? fmaxf(acc, 0.0f) : acc;
}

// ---------------- launch ----------------

extern "C" void kernel_launch(void* const* d_in, const int* in_sizes, int n_in,
                              void* d_out, int out_size, void* d_ws, size_t ws_size,
                              hipStream_t stream) {
    const float* row_embed = (const float*)d_in[0];
    const float* col_embed = (const float*)d_in[1];
    const float* W0 = (const float*)d_in[2];
    const float* b0 = (const float*)d_in[3];
    const float* W1 = (const float*)d_in[4];
    const float* b1 = (const float*)d_in[5];
    const float* W2 = (const float*)d_in[6];
    const float* b2 = (const float*)d_in[7];
    const int* ei = (const int*)d_in[8];
    const int* src = ei;
    const int* dst = ei + NEDGE;
    float* out = (float*)d_out;

    // workspace carve-up (~74 MB)
    __half* H = (__half*)d_ws;                                   // 9.6 MB
    float* B0 = (float*)(H + (size_t)NNODES * D);                // 19.2 MB
    unsigned int* binned = (unsigned int*)(B0 + (size_t)NNODES * D);  // 20 MB
    int* srcSorted = (int*)(binned + NEDGE);                     // 20 MB
    int* counts = srcSorted + NEDGE;                             // 2.4 MB
    int* bases = counts + NCOUNTS;                               // 2.4 MB
    int* partials = bases + NCOUNTS;                             // 586
    int* binPtr = partials + NSCAN;                              // NBINS+1
    int* rowptr = binPtr + (NBINS + 1);                          // NNODES+1

    const int row_grid = NNODES / 8;  // 18750 exact

    // CSR build — atomic-free counting sort (rebuilt every call; stateless)
    count_kernel<<<NBLK, SCT, 0, stream>>>(dst, counts);
    scanA<<<NSCAN, 256, 0, stream>>>(counts, partials);
    scanB<<<1, 256, 0, stream>>>(partials);
    scanC<<<NSCAN, 256, 0, stream>>>(counts, partials, bases, binPtr);
    scatter3<<<NBLK, SCT, 0, stream>>>(src, dst, bases, binned);
    fine_sort<<<NBINS, 512, 0, stream>>>(binPtr, binned, rowptr, srcSorted);

    // layer chain (unfused)
    linear_kernel<0><<<row_grid, 256, 0, stream>>>(row_embed, col_embed, W0, b0, H);
    agg_csr<false><<<row_grid, 256, 0, stream>>>(rowptr, srcSorted, H, B0);
    linear_kernel<1><<<row_grid, 256, 0, stream>>>(B0, nullptr, W1, b1, H);
    agg_csr<false><<<row_grid, 256, 0, stream>>>(rowptr, srcSorted, H, B0);
    linear_kernel<1><<<row_grid, 256, 0, stream>>>(B0, nullptr, W2, b2, H);
    agg_csr<true><<<row_grid, 256, 0, stream>>>(rowptr, srcSorted, H, out);

    (void)in_sizes; (void)n_in; (void)out_size; (void)ws_size;
}